// Round 2
// baseline (1086.820 us; speedup 1.0000x reference)
//
#include <hip/hip_runtime.h>
#include <cstdint>

typedef __attribute__((ext_vector_type(4))) float f32x4;

#define M_DIM 16384
#define N_DIM 4096
#define K_DIM 4096
#define KT (K_DIM / 64)   // 64 k-tiles of 64
#define GLOBAL_AS __attribute__((address_space(1)))
#define LDS_AS __attribute__((address_space(3)))

// ---------------------------------------------------------------------------
// FP4 fake-quant to fp8(e4m3) level codes.
// levels {0,0.5,1,1.5,2,3,4,6} -> e4m3 bytes {00,30,38,3C,40,44,48,4C}
// jnp.searchsorted(mids, a) side='left' == count of mids STRICTLY < a,
// reproduced with strict > comparisons on a = |v|/s (IEEE div, bit-identical).
// ---------------------------------------------------------------------------
__device__ __forceinline__ unsigned q1(float v, float s) {
  float a = fabsf(v) / s;
  int idx = (a > 0.25f) + (a > 0.75f) + (a > 1.25f) + (a > 1.75f)
          + (a > 2.5f)  + (a > 3.5f)  + (a > 5.0f);
  unsigned lo = 0x3C383000u, hi = 0x4C484440u;          // byte LUT in 2 regs
  unsigned b = (((idx < 4) ? lo : hi) >> ((idx & 3) * 8)) & 0xFFu;
  if (v < 0.0f) b |= 0x80u;
  return b;
}

// ---------------------------------------------------------------------------
// absmax reduction: vectorized f32x4, wave shfl-reduce, one atomic per block
// ---------------------------------------------------------------------------
__global__ __launch_bounds__(256) void amax_kernel(const float* __restrict__ p,
                                                   long long n4,
                                                   unsigned* __restrict__ out) {
  long long i = (long long)blockIdx.x * 256 + threadIdx.x;
  long long stride = (long long)gridDim.x * 256;
  float m = 0.0f;
  const f32x4* p4 = (const f32x4*)p;
  for (long long j = i; j < n4; j += stride) {
    f32x4 v = p4[j];
    m = fmaxf(m, fmaxf(fmaxf(fabsf(v.x), fabsf(v.y)),
                       fmaxf(fabsf(v.z), fabsf(v.w))));
  }
#pragma unroll
  for (int off = 32; off > 0; off >>= 1)
    m = fmaxf(m, __shfl_down(m, off, 64));
  __shared__ float smax[4];
  if ((threadIdx.x & 63) == 0) smax[threadIdx.x >> 6] = m;
  __syncthreads();
  if (threadIdx.x == 0) {
    m = fmaxf(fmaxf(smax[0], smax[1]), fmaxf(smax[2], smax[3]));
    atomicMax(out, __float_as_uint(m));   // all values >= 0: uint order == float order
  }
}

__global__ void scale_kernel(const unsigned* __restrict__ amax,
                             float* __restrict__ scales) {
  float sx = fmaxf(__uint_as_float(amax[0]) / 6.0f, 1e-12f);
  float sw = fmaxf(__uint_as_float(amax[1]) / 6.0f, 1e-12f);
  scales[0] = sx; scales[1] = sw; scales[2] = sx * sw;
}

// ---------------------------------------------------------------------------
// Pack x -> fp8 tiles in MFMA-fragment order.
// Tile (bm,kt) = 128 rows x 64 k = 8KB, laid out as
//   [frag = mi*2+kk][lane][8B],  frag row-group mi 0..7, k-half kk 0..1
//   lane holds A[mi*16 + (lane&15)][kk*32 + (lane>>4)*8 + j], j=0..7
// This equals the LDS image the GEMM consumes -> staging is a linear memcpy.
// ---------------------------------------------------------------------------
__global__ __launch_bounds__(256) void quantA_kernel(const float* __restrict__ x,
                                                     const float* __restrict__ scales,
                                                     unsigned long long* __restrict__ aq) {
  float s = scales[0];
  int bm = blockIdx.x / KT;
  int kt = blockIdx.x % KT;
  long long tile8 = (long long)blockIdx.x * 1024;
#pragma unroll
  for (int c = 0; c < 4; ++c) {
    int id = c * 256 + threadIdx.x;        // 0..1023 chunk of 8B
    int lane = id & 63;
    int frag = id >> 6;
    int mi = frag >> 1, kk = frag & 1;
    int row = bm * 128 + mi * 16 + (lane & 15);
    int col = kt * 64 + kk * 32 + (lane >> 4) * 8;
    const float* src = x + (long long)row * K_DIM + col;
    f32x4 v0 = *(const f32x4*)(src);
    f32x4 v1 = *(const f32x4*)(src + 4);
    unsigned long long o = 0;
    o |= (unsigned long long)q1(v0.x, s);
    o |= (unsigned long long)q1(v0.y, s) << 8;
    o |= (unsigned long long)q1(v0.z, s) << 16;
    o |= (unsigned long long)q1(v0.w, s) << 24;
    o |= (unsigned long long)q1(v1.x, s) << 32;
    o |= (unsigned long long)q1(v1.y, s) << 40;
    o |= (unsigned long long)q1(v1.z, s) << 48;
    o |= (unsigned long long)q1(v1.w, s) << 56;
    aq[tile8 + id] = o;
  }
}

// Pack W (K x N row-major) -> B^T fp8 tiles, fragment order:
//   lane holds B[kk*32 + (lane>>4)*8 + j][ni*16 + (lane&15)]  (8 k-gather)
__global__ __launch_bounds__(256) void quantB_kernel(const float* __restrict__ w,
                                                     const float* __restrict__ scales,
                                                     unsigned long long* __restrict__ bq) {
  float s = scales[1];
  int bn = blockIdx.x / KT;
  int kt = blockIdx.x % KT;
  long long tile8 = (long long)blockIdx.x * 1024;
#pragma unroll
  for (int c = 0; c < 4; ++c) {
    int id = c * 256 + threadIdx.x;
    int lane = id & 63;
    int frag = id >> 6;
    int ni = frag >> 1, kk = frag & 1;
    int n = bn * 128 + ni * 16 + (lane & 15);
    int k0 = kt * 64 + kk * 32 + (lane >> 4) * 8;
    unsigned long long o = 0;
#pragma unroll
    for (int j = 0; j < 8; ++j) {
      float v = w[(long long)(k0 + j) * N_DIM + n];
      o |= (unsigned long long)q1(v, s) << (8 * j);
    }
    bq[tile8 + id] = o;
  }
}

// ---------------------------------------------------------------------------
// 128x128 tile fp8 GEMM, m97 structure: global_load_lds(16B) staging,
// 2 barriers per K-step (BK=64), 4 waves each owning a 64x64 subtile,
// 16x16x32 fp8_fp8 MFMA, fp32 accum. Epilogue: *= s_x*s_w, += bias.
// ---------------------------------------------------------------------------
__global__ __launch_bounds__(256) void gemm_kernel(
    const unsigned long long* __restrict__ aq,
    const unsigned long long* __restrict__ bq,
    const float* __restrict__ bias,
    const float* __restrict__ scales,
    float* __restrict__ out) {
  __shared__ unsigned long long As[1024];  // 8KB = one A tile image
  __shared__ unsigned long long Bs[1024];  // 8KB = one B tile image

  // XCD-aware swizzle (grid 4096 % 8 == 0 -> simple form is bijective)
  int cpx = gridDim.x >> 3;
  int bid = blockIdx.x;
  int swz = (bid & 7) * cpx + (bid >> 3);
  int bm = swz / (N_DIM / 128);
  int bn = swz % (N_DIM / 128);

  int tid = threadIdx.x;
  int wave = tid >> 6, lane = tid & 63;
  int wrow = wave >> 1, wcol = wave & 1;

  f32x4 acc[4][4] = {};
  const char* ag0 = (const char*)(aq + (long long)bm * KT * 1024);
  const char* bg0 = (const char*)(bq + (long long)bn * KT * 1024);
  char* lAs = (char*)As;
  char* lBs = (char*)Bs;

  for (int kt = 0; kt < KT; ++kt) {
    const char* ag = ag0 + (long long)kt * 8192;
    const char* bg = bg0 + (long long)kt * 8192;
#pragma unroll
    for (int r = 0; r < 2; ++r) {
      int off = r * 4096 + wave * 1024;   // wave-uniform LDS base; HW adds lane*16
      __builtin_amdgcn_global_load_lds((const GLOBAL_AS void*)(ag + off + lane * 16),
                                       (LDS_AS void*)(lAs + off), 16, 0, 0);
      __builtin_amdgcn_global_load_lds((const GLOBAL_AS void*)(bg + off + lane * 16),
                                       (LDS_AS void*)(lBs + off), 16, 0, 0);
    }
    __syncthreads();   // compiler drains vmcnt before s_barrier
#pragma unroll
    for (int kk = 0; kk < 2; ++kk) {
      long a_frag[4], b_frag[4];
#pragma unroll
      for (int i = 0; i < 4; ++i) {
        a_frag[i] = (long)As[((wrow * 4 + i) * 2 + kk) * 64 + lane];  // lane-linear: 0 conflicts
        b_frag[i] = (long)Bs[((wcol * 4 + i) * 2 + kk) * 64 + lane];
      }
#pragma unroll
      for (int i = 0; i < 4; ++i)
#pragma unroll
        for (int j = 0; j < 4; ++j)
          acc[i][j] = __builtin_amdgcn_mfma_f32_16x16x32_fp8_fp8(
              a_frag[i], b_frag[j], acc[i][j], 0, 0, 0);
    }
    __syncthreads();
  }

  float s = scales[2];
#pragma unroll
  for (int i = 0; i < 4; ++i) {
    int row0 = bm * 128 + wrow * 64 + i * 16 + ((lane >> 4) << 2);  // C/D: row=(lane>>4)*4+reg
#pragma unroll
    for (int j = 0; j < 4; ++j) {
      int col = bn * 128 + wcol * 64 + j * 16 + (lane & 15);        // C/D: col=lane&15
      float bv = bias[col];
#pragma unroll
      for (int r = 0; r < 4; ++r)
        out[(long long)(row0 + r) * N_DIM + col] = acc[i][j][r] * s + bv;
    }
  }
}

// ---------------------------------------------------------------------------
extern "C" void kernel_launch(void* const* d_in, const int* in_sizes, int n_in,
                              void* d_out, int out_size, void* d_ws, size_t ws_size,
                              hipStream_t stream) {
  const float* x    = (const float*)d_in[0];   // [16384, 4096]
  const float* w    = (const float*)d_in[1];   // [4096, 4096]
  const float* bias = (const float*)d_in[2];   // [4096]
  float* out = (float*)d_out;

  char* ws = (char*)d_ws;
  unsigned* amax = (unsigned*)ws;                                   // 2 x u32
  float* scales  = (float*)(ws + 64);                               // sx, sw, sx*sw
  unsigned long long* aq = (unsigned long long*)(ws + 256);         // 64 MB packed fp8 x
  unsigned long long* bq = (unsigned long long*)(ws + 256 + (long long)M_DIM * K_DIM); // 16 MB

  hipMemsetAsync(amax, 0, 8, stream);  // ws is poisoned 0xAA; atomicMax needs 0 init
  amax_kernel<<<2048, 256, 0, stream>>>(x, (long long)M_DIM * K_DIM / 4, amax + 0);
  amax_kernel<<<1024, 256, 0, stream>>>(w, (long long)K_DIM * N_DIM / 4, amax + 1);
  scale_kernel<<<1, 1, 0, stream>>>(amax, scales);
  quantA_kernel<<<(M_DIM / 128) * KT, 256, 0, stream>>>(x, scales, aq);
  quantB_kernel<<<(N_DIM / 128) * KT, 256, 0, stream>>>(w, scales, bq);
  gemm_kernel<<<(M_DIM / 128) * (N_DIM / 128), 256, 0, stream>>>(aq, bq, bias, scales, out);
}